// Round 11
// baseline (401.445 us; speedup 1.0000x reference)
//
#include <hip/hip_runtime.h>
#include <hip/hip_bf16.h>
#include <math.h>

#define N 8192
#define FIN 256
#define D 64
#define ALPHA 0.2f
#define NSPLIT 8
#define CS 1024            // columns per split
#define NSS 8              // super-steps per slab (128 cols each)
#define SROW 528           // staged mask row: 512 B + 16 pad
#define WBUF (16 * SROW)   // 8448 B per wave per buffer

typedef __attribute__((ext_vector_type(8))) short bf16x8;
typedef __attribute__((ext_vector_type(4))) float f32x4;

// ---------------- Kernel 1: h = x@trans (fp32), e1/e2 (fp32), hF fragment-order
__global__ __launch_bounds__(256) void k_h_e(
    const float* __restrict__ x, const float* __restrict__ trans,
    const float* __restrict__ attn,
    __hip_bfloat16* __restrict__ hF, float* __restrict__ e1, float* __restrict__ e2)
{
    __shared__ float xs[8 * FIN];
    __shared__ __hip_bfloat16 hl[8 * D];
    const int t = threadIdx.x;
    const int r0 = blockIdx.x * 8;

    #pragma unroll
    for (int v = 0; v < 2; ++v) {
        int idx = t + 256 * v;
        ((float4*)xs)[idx] = ((const float4*)(x + (size_t)r0 * FIN))[idx];
    }
    __syncthreads();

    const int lane = t & 63, w = t >> 6;
    const float* xa = xs + (2 * w) * FIN;
    const float* xb = xs + (2 * w + 1) * FIN;
    float acca = 0.f, accb = 0.f;
    #pragma unroll 8
    for (int k = 0; k < FIN; ++k) {
        const float tv = trans[k * D + lane];
        acca = fmaf(xa[k], tv, acca);
        accb = fmaf(xb[k], tv, accb);
    }
    const int ra = r0 + 2 * w, rb = ra + 1;

    const float a1 = attn[lane], a2 = attn[D + lane];
    float p1a = acca * a1, p2a = acca * a2;
    float p1b = accb * a1, p2b = accb * a2;
    #pragma unroll
    for (int mm = 1; mm <= 32; mm <<= 1) {
        p1a += __shfl_xor(p1a, mm);
        p2a += __shfl_xor(p2a, mm);
        p1b += __shfl_xor(p1b, mm);
        p2b += __shfl_xor(p2b, mm);
    }
    if (lane == 0) { e1[ra] = p1a; e2[ra] = p2a; e1[rb] = p1b; e2[rb] = p2b; }

    hl[(2 * w) * D + lane]     = __float2bfloat16(acca);
    hl[(2 * w + 1) * D + lane] = __float2bfloat16(accb);
    __syncthreads();
    if (t < D) {
        const int q = t >> 4, m = t & 15;
        const int cb = r0 >> 5, jgrp = (r0 >> 3) & 3;
        union { bf16x8 v; __hip_bfloat16 h[8]; } o;
        #pragma unroll
        for (int r = 0; r < 8; ++r) o.h[r] = hl[r * D + q * 16 + m];
        *(bf16x8*)(hF + (((size_t)cb * 4 + q) * 64 + jgrp * 16 + m) * 8) = o.v;
    }
}

// ---------------- Kernel 2: pipelined masked softmax-attention via MFMA --------
// In-order vmcnt pipeline: per super-step, wait vmcnt(16) [drains mask DMA(ss)
// only], issue DMA(ss+1) (other buffer), hoist hF(ss+1) regs, compute(ss) with
// ZERO global register loads (mask+e2 from LDS, hF from hoisted regs older than
// DMA(ss+1)). The mask HBM stream thus flows CONTINUOUSLY under compute.

#define GLDS(G, L, SZ) __builtin_amdgcn_global_load_lds( \
    (const __attribute__((address_space(1))) void*)(G),  \
    (__attribute__((address_space(3))) void*)(L), (SZ), 0, 0)

#define STAGE_MASK(SSV, BUF)                                           \
    {                                                                  \
        const int cb_ = c0 + (SSV) * 128;                              \
        _Pragma("unroll")                                              \
        for (int r_ = 0; r_ < 16; ++r_) {                              \
            const int* g_ = mask + (size_t)(i0 + r_) * N + cb_ + lane; \
            char* l_ = (BUF) + r_ * SROW + lane * 4;                   \
            GLDS(g_, l_, 4);                                           \
            GLDS(g_ + 64, l_ + 256, 4);                                \
        }                                                              \
    }

#define HOIST_HF(SSV, HX)                                              \
    {                                                                  \
        _Pragma("unroll")                                              \
        for (int p_ = 0; p_ < 4; ++p_) {                               \
            const size_t ito_ = (size_t)((SSV) * 4 + p_) * 2048;       \
            HX[4 * p_ + 0] = *(const bf16x8*)(hfp + ito_);             \
            HX[4 * p_ + 1] = *(const bf16x8*)(hfp + ito_ + 512);       \
            HX[4 * p_ + 2] = *(const bf16x8*)(hfp + ito_ + 1024);      \
            HX[4 * p_ + 3] = *(const bf16x8*)(hfp + ito_ + 1536);      \
        }                                                              \
    }

#define COMPUTE_SS(SSV, BUF, HX)                                               \
    {                                                                          \
        const char* swm_ = (BUF) + m * SROW;                                   \
        _Pragma("unroll")                                                      \
        for (int p_ = 0; p_ < 4; ++p_) {                                       \
            const int4 m0 = *(const int4*)(swm_ + p_ * 128 + quad * 32);       \
            const int4 m1 = *(const int4*)(swm_ + p_ * 128 + quad * 32 + 16);  \
            const int ec_ = (SSV) * 128 + p_ * 32 + quad * 8;                  \
            const float4 ea = *(const float4*)(se2 + ec_);                     \
            const float4 eb = *(const float4*)(se2 + ec_ + 4);                 \
            float s0 = er + ea.x; s0 = s0 > 0.f ? s0 : ALPHA * s0;             \
            float s1 = er + ea.y; s1 = s1 > 0.f ? s1 : ALPHA * s1;             \
            float s2 = er + ea.z; s2 = s2 > 0.f ? s2 : ALPHA * s2;             \
            float s3 = er + ea.w; s3 = s3 > 0.f ? s3 : ALPHA * s3;             \
            float s4 = er + eb.x; s4 = s4 > 0.f ? s4 : ALPHA * s4;             \
            float s5 = er + eb.y; s5 = s5 > 0.f ? s5 : ALPHA * s5;             \
            float s6 = er + eb.z; s6 = s6 > 0.f ? s6 : ALPHA * s6;             \
            float s7 = er + eb.w; s7 = s7 > 0.f ? s7 : ALPHA * s7;             \
            const float p0 = m0.x ? __expf(s0) : 0.f;                          \
            const float p1 = m0.y ? __expf(s1) : 0.f;                          \
            const float p2 = m0.z ? __expf(s2) : 0.f;                          \
            const float p3 = m0.w ? __expf(s3) : 0.f;                          \
            const float p4 = m1.x ? __expf(s4) : 0.f;                          \
            const float p5 = m1.y ? __expf(s5) : 0.f;                          \
            const float p6 = m1.z ? __expf(s6) : 0.f;                          \
            const float p7 = m1.w ? __expf(s7) : 0.f;                          \
            union { bf16x8 v; __hip_bfloat162 h2[4]; } af;                     \
            af.h2[0] = __float22bfloat162_rn(make_float2(p0, p1));             \
            af.h2[1] = __float22bfloat162_rn(make_float2(p2, p3));             \
            af.h2[2] = __float22bfloat162_rn(make_float2(p4, p5));             \
            af.h2[3] = __float22bfloat162_rn(make_float2(p6, p7));             \
            lsum += ((p0 + p1) + (p2 + p3)) + ((p4 + p5) + (p6 + p7));         \
            acc0 = __builtin_amdgcn_mfma_f32_16x16x32_bf16(af.v, HX[4*p_+0], acc0, 0, 0, 0); \
            acc1 = __builtin_amdgcn_mfma_f32_16x16x32_bf16(af.v, HX[4*p_+1], acc1, 0, 0, 0); \
            acc2 = __builtin_amdgcn_mfma_f32_16x16x32_bf16(af.v, HX[4*p_+2], acc2, 0, 0, 0); \
            acc3 = __builtin_amdgcn_mfma_f32_16x16x32_bf16(af.v, HX[4*p_+3], acc3, 0, 0, 0); \
        }                                                                      \
    }

__global__ __launch_bounds__(256, 2) void k_attn(
    const int* __restrict__ mask, const __hip_bfloat16* __restrict__ hF,
    const float* __restrict__ e1, const float* __restrict__ e2,
    float* __restrict__ acc_part, float* __restrict__ l_part)
{
    __shared__ __align__(16) char smask[8 * WBUF];   // 2 bufs x 4 waves = 66 KB
    __shared__ __align__(16) float se2[CS];          // 4 KB, block-shared
    const int t = threadIdx.x;
    const int lane = t & 63, wave = t >> 6;
    const int i0 = (blockIdx.y * 4 + wave) * 16;
    const int sp = blockIdx.x;
    const int c0 = sp * CS;
    const int m = lane & 15, quad = lane >> 4;
    const int row = i0 + m;
    const float er = e1[row];

    char* bufA = smask + (wave * 2 + 0) * WBUF;
    char* bufB = smask + (wave * 2 + 1) * WBUF;
    const __hip_bfloat16* hfp = hF + (((size_t)(c0 >> 5)) * 4 * 64 + lane) * 8;

    f32x4 acc0 = {0.f, 0.f, 0.f, 0.f};
    f32x4 acc1 = {0.f, 0.f, 0.f, 0.f};
    f32x4 acc2 = {0.f, 0.f, 0.f, 0.f};
    f32x4 acc3 = {0.f, 0.f, 0.f, 0.f};
    float lsum = 0.f;
    bf16x8 hA[16], hB[16];

    // ---- prologue: e2 slab -> LDS (wave 0); mask SS0 -> bufA; hoist hF SS0
    if (wave == 0) {
        #pragma unroll
        for (int i = 0; i < 16; ++i)
            GLDS(e2 + c0 + i * 64 + lane, (char*)se2 + i * 256 + lane * 4, 4);
    }
    STAGE_MASK(0, bufA);
    HOIST_HF(0, hA);
    __syncthreads();   // compiler drains vmcnt(0) here: se2 + mask(0) + hA ready

    for (int s2 = 0; s2 < NSS; s2 += 2) {
        // even SS: mask(s2) guaranteed (vmcnt(16) keeps the 16 newest = hA/hB)
        __builtin_amdgcn_s_waitcnt(0x4F70);          // vmcnt(16)
        STAGE_MASK(s2 + 1, bufB);
        HOIST_HF(s2 + 1, hB);
        COMPUTE_SS(s2, bufA, hA);
        // odd SS
        __builtin_amdgcn_s_waitcnt(0x4F70);          // vmcnt(16)
        {
            const int sn = (s2 + 2 < NSS) ? s2 + 2 : s2 + 1;
            STAGE_MASK(sn, bufA);
            HOIST_HF(sn, hA);
        }
        COMPUTE_SS(s2 + 1, bufB, hB);
    }
    __builtin_amdgcn_s_waitcnt(0x0F70);   // vmcnt(0): no DMA outstanding at endpgm

    lsum += __shfl_xor(lsum, 16);
    lsum += __shfl_xor(lsum, 32);
    if (quad == 0) l_part[(size_t)sp * N + row] = lsum;

    // C/D layout: col = lane&15 (+16 per acc frag), row = quad*4 + reg
    #pragma unroll
    for (int reg = 0; reg < 4; ++reg) {
        const size_t rbase = ((size_t)sp * N + i0 + quad * 4 + reg) * D;
        acc_part[rbase + m     ] = acc0[reg];
        acc_part[rbase + m + 16] = acc1[reg];
        acc_part[rbase + m + 32] = acc2[reg];
        acc_part[rbase + m + 48] = acc3[reg];
    }
}

// ---------------- Kernel 3: combine splits, divide by l ------------------------
__global__ __launch_bounds__(256) void k_reduce(
    const float* __restrict__ acc_part, const float* __restrict__ l_part,
    float* __restrict__ out, int nsplit)
{
    const int idx = blockIdx.x * 256 + threadIdx.x;
    const int row = idx >> 6;
    float sum = 0.f, l = 0.f;
    for (int s = 0; s < nsplit; ++s) {
        sum += acc_part[(size_t)s * N * D + idx];
        l   += l_part[(size_t)s * N + row];
    }
    out[idx] = sum / l;
}

extern "C" void kernel_launch(void* const* d_in, const int* in_sizes, int n_in,
                              void* d_out, int out_size, void* d_ws, size_t ws_size,
                              hipStream_t stream) {
    const float* x     = (const float*)d_in[0];
    const int*   mask  = (const int*)d_in[1];
    const float* trans = (const float*)d_in[2];
    const float* attn  = (const float*)d_in[3];
    float* out = (float*)d_out;

    char* ws = (char*)d_ws;
    __hip_bfloat16* hF = (__hip_bfloat16*)ws;                 // 1 MB
    char* p = ws + (size_t)D * N * sizeof(__hip_bfloat16);
    float* e1 = (float*)p;            p += (size_t)N * sizeof(float);
    float* e2 = (float*)p;            p += (size_t)N * sizeof(float);
    float* l_part = (float*)p;        p += (size_t)NSPLIT * N * sizeof(float);
    float* acc_part = (float*)p;      // NSPLIT * N * D floats = 16 MB (ws is 1 GiB)

    k_h_e<<<N / 8, 256, 0, stream>>>(x, trans, attn, hF, e1, e2);
    dim3 g2(NSPLIT, N / 64);
    k_attn<<<g2, 256, 0, stream>>>(mask, hF, e1, e2, acc_part, l_part);
    k_reduce<<<(N * D) / 256, 256, 0, stream>>>(acc_part, l_part, out, NSPLIT);
}

// Round 12
// 383.962 us; speedup vs baseline: 1.0455x; 1.0455x over previous
//
#include <hip/hip_runtime.h>
#include <hip/hip_bf16.h>
#include <math.h>

#define N 8192
#define FIN 256
#define D 64
#define ALPHA 0.2f
#define SROW 1040   // LDS bytes per staged mask row: 1024 + 16 pad (bank spread)
#define WBUF (16 * SROW)   // 16.25 KB per wave

typedef __attribute__((ext_vector_type(8))) short bf16x8;
typedef __attribute__((ext_vector_type(4))) float f32x4;

// ---------------- Kernel 1: h = x@trans (fp32), e1/e2 (fp32), hF fragment-order
__global__ __launch_bounds__(256) void k_h_e(
    const float* __restrict__ x, const float* __restrict__ trans,
    const float* __restrict__ attn,
    __hip_bfloat16* __restrict__ hF, float* __restrict__ e1, float* __restrict__ e2)
{
    __shared__ float xs[8 * FIN];
    __shared__ __hip_bfloat16 hl[8 * D];
    const int t = threadIdx.x;
    const int r0 = blockIdx.x * 8;

    #pragma unroll
    for (int v = 0; v < 2; ++v) {
        int idx = t + 256 * v;
        ((float4*)xs)[idx] = ((const float4*)(x + (size_t)r0 * FIN))[idx];
    }
    __syncthreads();

    const int lane = t & 63, w = t >> 6;
    const float* xa = xs + (2 * w) * FIN;
    const float* xb = xs + (2 * w + 1) * FIN;
    float acca = 0.f, accb = 0.f;
    #pragma unroll 8
    for (int k = 0; k < FIN; ++k) {
        const float tv = trans[k * D + lane];
        acca = fmaf(xa[k], tv, acca);
        accb = fmaf(xb[k], tv, accb);
    }
    const int ra = r0 + 2 * w, rb = ra + 1;

    const float a1 = attn[lane], a2 = attn[D + lane];
    float p1a = acca * a1, p2a = acca * a2;
    float p1b = accb * a1, p2b = accb * a2;
    #pragma unroll
    for (int mm = 1; mm <= 32; mm <<= 1) {
        p1a += __shfl_xor(p1a, mm);
        p2a += __shfl_xor(p2a, mm);
        p1b += __shfl_xor(p1b, mm);
        p2b += __shfl_xor(p2b, mm);
    }
    if (lane == 0) { e1[ra] = p1a; e2[ra] = p2a; e1[rb] = p1b; e2[rb] = p2b; }

    hl[(2 * w) * D + lane]     = __float2bfloat16(acca);
    hl[(2 * w + 1) * D + lane] = __float2bfloat16(accb);
    __syncthreads();
    if (t < D) {
        const int q = t >> 4, m = t & 15;
        const int cb = r0 >> 5, jgrp = (r0 >> 3) & 3;
        union { bf16x8 v; __hip_bfloat16 h[8]; } o;
        #pragma unroll
        for (int r = 0; r < 8; ++r) o.h[r] = hl[r * D + q * 16 + m];
        *(bf16x8*)(hF + (((size_t)cb * 4 + q) * 64 + jgrp * 16 + m) * 8) = o.v;
    }
}

// ---------------- Kernel 2: fused masked softmax-attention via MFMA ------------
// R10 structure (best-known: wave-private 16-row x 1KB mask tiles via
// global_load_lds, oldest-first consumption, hF/e2 1-iter register prefetch).
// SINGLE CHANGE vs R10: mask DMA uses aux=2 -> `nt` (non-temporal): no L3
// allocation on the 256-MB streaming read => no dirty-victim eviction tax from
// the harness's 1-GiB 0xAA poison fill that precedes every timed launch.
__global__ __launch_bounds__(256) void k_attn(
    const int* __restrict__ mask, const __hip_bfloat16* __restrict__ hF,
    const float* __restrict__ e1, const float* __restrict__ e2,
    float* __restrict__ acc_part, float* __restrict__ l_part, int cs)
{
    __shared__ __align__(16) char smem[4 * WBUF];   // 66.5 KB -> 2 blocks/CU
    const int t = threadIdx.x;
    const int lane = t & 63, wave = t >> 6;
    const int i0 = (blockIdx.y * 4 + wave) * 16;
    const int sp = blockIdx.x;
    const int c0 = sp * cs;
    const int m = lane & 15, quad = lane >> 4;
    const int row = i0 + m;
    const float er = e1[row];

    char* sw = smem + wave * WBUF;
    const char* swm = sw + m * SROW;
    const __hip_bfloat16* hfp = hF + (((size_t)(c0 >> 5)) * 4 * 64 + lane) * 8;

    f32x4 acc0 = {0.f, 0.f, 0.f, 0.f};
    f32x4 acc1 = {0.f, 0.f, 0.f, 0.f};
    f32x4 acc2 = {0.f, 0.f, 0.f, 0.f};
    f32x4 acc3 = {0.f, 0.f, 0.f, 0.f};
    float lsum = 0.f;

    const int nss = cs >> 8;   // super-steps of 8 iterations (256 cols) each

    for (int ss = 0; ss < nss; ++ss) {
        const int cb0 = c0 + ss * 256;
        // ---- stage: 16 rows x 1 KB contiguous, lane i -> bytes [16i,16i+16)
        #pragma unroll
        for (int r = 0; r < 16; ++r) {
            const int* g = mask + (size_t)(i0 + r) * N + cb0 + lane * 4;
            char* l = sw + r * SROW + lane * 16;
            __builtin_amdgcn_global_load_lds(
                (const __attribute__((address_space(1))) void*)g,
                (__attribute__((address_space(3))) void*)l, 16, 0, 2 /* nt */);
        }
        __builtin_amdgcn_s_waitcnt(0x0F70);   // vmcnt(0): LDS tile ready

        const int itg0 = ss * 8;
        // prefetch iter 0's hF/e2
        bf16x8 pb0, pb1, pb2, pb3; float4 pea, peb;
        {
            const size_t ito = (size_t)itg0 * 2048;
            pb0 = *(const bf16x8*)(hfp + ito);
            pb1 = *(const bf16x8*)(hfp + ito + 512);
            pb2 = *(const bf16x8*)(hfp + ito + 1024);
            pb3 = *(const bf16x8*)(hfp + ito + 1536);
            const int jb = cb0 + quad * 8;
            pea = *(const float4*)(e2 + jb);
            peb = *(const float4*)(e2 + jb + 4);
        }
        #pragma unroll
        for (int p = 0; p < 8; ++p) {
            const bf16x8 b0 = pb0, b1 = pb1, b2 = pb2, b3 = pb3;
            const float4 ea = pea, eb = peb;
            if (p < 7) {   // issue iter p+1's loads BEFORE consuming iter p
                const size_t ito = (size_t)(itg0 + p + 1) * 2048;
                pb0 = *(const bf16x8*)(hfp + ito);
                pb1 = *(const bf16x8*)(hfp + ito + 512);
                pb2 = *(const bf16x8*)(hfp + ito + 1024);
                pb3 = *(const bf16x8*)(hfp + ito + 1536);
                const int jb = cb0 + (p + 1) * 32 + quad * 8;
                pea = *(const float4*)(e2 + jb);
                peb = *(const float4*)(e2 + jb + 4);
            }
            // mask from LDS (2-way bank aliasing only -> free)
            const int4 m0 = *(const int4*)(swm + p * 128 + quad * 32);
            const int4 m1 = *(const int4*)(swm + p * 128 + quad * 32 + 16);

            float s0 = er + ea.x; s0 = s0 > 0.f ? s0 : ALPHA * s0;
            float s1 = er + ea.y; s1 = s1 > 0.f ? s1 : ALPHA * s1;
            float s2 = er + ea.z; s2 = s2 > 0.f ? s2 : ALPHA * s2;
            float s3 = er + ea.w; s3 = s3 > 0.f ? s3 : ALPHA * s3;
            float s4 = er + eb.x; s4 = s4 > 0.f ? s4 : ALPHA * s4;
            float s5 = er + eb.y; s5 = s5 > 0.f ? s5 : ALPHA * s5;
            float s6 = er + eb.z; s6 = s6 > 0.f ? s6 : ALPHA * s6;
            float s7 = er + eb.w; s7 = s7 > 0.f ? s7 : ALPHA * s7;
            const float p0 = m0.x ? __expf(s0) : 0.f;
            const float p1 = m0.y ? __expf(s1) : 0.f;
            const float p2 = m0.z ? __expf(s2) : 0.f;
            const float p3 = m0.w ? __expf(s3) : 0.f;
            const float p4 = m1.x ? __expf(s4) : 0.f;
            const float p5 = m1.y ? __expf(s5) : 0.f;
            const float p6 = m1.z ? __expf(s6) : 0.f;
            const float p7 = m1.w ? __expf(s7) : 0.f;

            union { bf16x8 v; __hip_bfloat162 h2[4]; } af;
            af.h2[0] = __float22bfloat162_rn(make_float2(p0, p1));
            af.h2[1] = __float22bfloat162_rn(make_float2(p2, p3));
            af.h2[2] = __float22bfloat162_rn(make_float2(p4, p5));
            af.h2[3] = __float22bfloat162_rn(make_float2(p6, p7));

            lsum += ((p0 + p1) + (p2 + p3)) + ((p4 + p5) + (p6 + p7));

            acc0 = __builtin_amdgcn_mfma_f32_16x16x32_bf16(af.v, b0, acc0, 0, 0, 0);
            acc1 = __builtin_amdgcn_mfma_f32_16x16x32_bf16(af.v, b1, acc1, 0, 0, 0);
            acc2 = __builtin_amdgcn_mfma_f32_16x16x32_bf16(af.v, b2, acc2, 0, 0, 0);
            acc3 = __builtin_amdgcn_mfma_f32_16x16x32_bf16(af.v, b3, acc3, 0, 0, 0);
        }
    }

    lsum += __shfl_xor(lsum, 16);
    lsum += __shfl_xor(lsum, 32);
    if (quad == 0) l_part[(size_t)sp * N + row] = lsum;

    // C/D layout: col = lane&15 (+16 per acc frag), row = quad*4 + reg
    #pragma unroll
    for (int reg = 0; reg < 4; ++reg) {
        const size_t rbase = ((size_t)sp * N + i0 + quad * 4 + reg) * D;
        acc_part[rbase + m     ] = acc0[reg];
        acc_part[rbase + m + 16] = acc1[reg];
        acc_part[rbase + m + 32] = acc2[reg];
        acc_part[rbase + m + 48] = acc3[reg];
    }
}

// ---------------- Kernel 3: combine splits, divide by l ------------------------
__global__ __launch_bounds__(256) void k_reduce(
    const float* __restrict__ acc_part, const float* __restrict__ l_part,
    float* __restrict__ out, int nsplit)
{
    const int idx = blockIdx.x * 256 + threadIdx.x;
    const int row = idx >> 6;
    float sum = 0.f, l = 0.f;
    for (int s = 0; s < nsplit; ++s) {
        sum += acc_part[(size_t)s * N * D + idx];
        l   += l_part[(size_t)s * N + row];
    }
    out[idx] = sum / l;
}

extern "C" void kernel_launch(void* const* d_in, const int* in_sizes, int n_in,
                              void* d_out, int out_size, void* d_ws, size_t ws_size,
                              hipStream_t stream) {
    const float* x     = (const float*)d_in[0];
    const int*   mask  = (const int*)d_in[1];
    const float* trans = (const float*)d_in[2];
    const float* attn  = (const float*)d_in[3];
    float* out = (float*)d_out;

    char* ws = (char*)d_ws;
    __hip_bfloat16* hF = (__hip_bfloat16*)ws;                 // 1 MB
    char* p = ws + (size_t)D * N * sizeof(__hip_bfloat16);
    float* e1 = (float*)p;            p += (size_t)N * sizeof(float);
    float* e2 = (float*)p;            p += (size_t)N * sizeof(float);

    const size_t used = (size_t)(p - ws);
    int nsplit = 4;                    // 512 blocks = exactly 2 resident/CU
    while (nsplit > 1) {
        size_t need = used + (size_t)nsplit * N * sizeof(float)
                    + (size_t)nsplit * N * D * sizeof(float);
        if (need <= ws_size) break;
        nsplit >>= 1;
    }
    float* l_part = (float*)p;
    float* acc_part = l_part + (size_t)nsplit * N;

    k_h_e<<<N / 8, 256, 0, stream>>>(x, trans, attn, hF, e1, e2);
    dim3 g2(nsplit, N / 64);
    k_attn<<<g2, 256, 0, stream>>>(mask, hF, e1, e2, acc_part, l_part, N / nsplit);
    k_reduce<<<(N * D) / 256, 256, 0, stream>>>(acc_part, l_part, out, nsplit);
}

// Round 13
// 382.775 us; speedup vs baseline: 1.0488x; 1.0031x over previous
//
#include <hip/hip_runtime.h>
#include <hip/hip_bf16.h>
#include <math.h>

#define N 8192
#define FIN 256
#define D 64
#define ALPHA 0.2f
#define SROW 1040          // staged mask row: 1024 B + 16 pad (bank spread)
#define WBUF (16 * SROW)   // 16.25 KB per wave
#define CS 2048            // columns per wave (4 waves cover N)

typedef __attribute__((ext_vector_type(8))) short bf16x8;
typedef __attribute__((ext_vector_type(4))) float f32x4;

// ---------------- Kernel 1: h = x@trans (fp32), e1/e2 (fp32), hF fragment-order
__global__ __launch_bounds__(256) void k_h_e(
    const float* __restrict__ x, const float* __restrict__ trans,
    const float* __restrict__ attn,
    __hip_bfloat16* __restrict__ hF, float* __restrict__ e1, float* __restrict__ e2)
{
    __shared__ float xs[8 * FIN];
    __shared__ __hip_bfloat16 hl[8 * D];
    const int t = threadIdx.x;
    const int r0 = blockIdx.x * 8;

    #pragma unroll
    for (int v = 0; v < 2; ++v) {
        int idx = t + 256 * v;
        ((float4*)xs)[idx] = ((const float4*)(x + (size_t)r0 * FIN))[idx];
    }
    __syncthreads();

    const int lane = t & 63, w = t >> 6;
    const float* xa = xs + (2 * w) * FIN;
    const float* xb = xs + (2 * w + 1) * FIN;
    float acca = 0.f, accb = 0.f;
    #pragma unroll 8
    for (int k = 0; k < FIN; ++k) {
        const float tv = trans[k * D + lane];
        acca = fmaf(xa[k], tv, acca);
        accb = fmaf(xb[k], tv, accb);
    }
    const int ra = r0 + 2 * w, rb = ra + 1;

    const float a1 = attn[lane], a2 = attn[D + lane];
    float p1a = acca * a1, p2a = acca * a2;
    float p1b = accb * a1, p2b = accb * a2;
    #pragma unroll
    for (int mm = 1; mm <= 32; mm <<= 1) {
        p1a += __shfl_xor(p1a, mm);
        p2a += __shfl_xor(p2a, mm);
        p1b += __shfl_xor(p1b, mm);
        p2b += __shfl_xor(p2b, mm);
    }
    if (lane == 0) { e1[ra] = p1a; e2[ra] = p2a; e1[rb] = p1b; e2[rb] = p2b; }

    hl[(2 * w) * D + lane]     = __float2bfloat16(acca);
    hl[(2 * w + 1) * D + lane] = __float2bfloat16(accb);
    __syncthreads();
    if (t < D) {
        const int q = t >> 4, m = t & 15;
        const int cb = r0 >> 5, jgrp = (r0 >> 3) & 3;
        union { bf16x8 v; __hip_bfloat16 h[8]; } o;
        #pragma unroll
        for (int r = 0; r < 8; ++r) o.h[r] = hl[r * D + q * 16 + m];
        *(bf16x8*)(hF + (((size_t)cb * 4 + q) * 64 + jgrp * 16 + m) * 8) = o.v;
    }
}

// ---------------- Kernel 2: fully-fused masked softmax-attention ---------------
// Block owns 16 rows x ALL 8192 cols; wave w covers cols [2048w, 2048w+2048)
// (identical partition + combine order as the old nsplit=4 + k_reduce path ->
// bit-identical numerics). Mask staged via nt global_load_lds (R12). Cross-wave
// combine + softmax divide in LDS (aliased over the dead mask buffers); out
// written directly -- no acc_part round-trip, no 4th kernel.
__global__ __launch_bounds__(256) void k_attn(
    const int* __restrict__ mask, const __hip_bfloat16* __restrict__ hF,
    const float* __restrict__ e1, const float* __restrict__ e2,
    float* __restrict__ out)
{
    __shared__ __align__(16) char smem[4 * WBUF];   // 66.5 KB -> 2 blocks/CU
    __shared__ float lw[4][16];
    const int t = threadIdx.x;
    const int lane = t & 63, wave = t >> 6;
    const int i0 = blockIdx.x * 16;
    const int c0 = wave * CS;
    const int m = lane & 15, quad = lane >> 4;
    const int row = i0 + m;
    const float er = e1[row];

    char* sw = smem + wave * WBUF;
    const char* swm = sw + m * SROW;
    const __hip_bfloat16* hfp = hF + (((size_t)(c0 >> 5)) * 4 * 64 + lane) * 8;

    f32x4 acc0 = {0.f, 0.f, 0.f, 0.f};
    f32x4 acc1 = {0.f, 0.f, 0.f, 0.f};
    f32x4 acc2 = {0.f, 0.f, 0.f, 0.f};
    f32x4 acc3 = {0.f, 0.f, 0.f, 0.f};
    float lsum = 0.f;

    const int nss = CS >> 8;   // 8 super-steps of 8 iterations (256 cols) each

    for (int ss = 0; ss < nss; ++ss) {
        const int cb0 = c0 + ss * 256;
        // ---- stage: 16 rows x 1 KB contiguous, lane i -> bytes [16i,16i+16)
        #pragma unroll
        for (int r = 0; r < 16; ++r) {
            const int* g = mask + (size_t)(i0 + r) * N + cb0 + lane * 4;
            char* l = sw + r * SROW + lane * 16;
            __builtin_amdgcn_global_load_lds(
                (const __attribute__((address_space(1))) void*)g,
                (__attribute__((address_space(3))) void*)l, 16, 0, 2 /* nt */);
        }
        __builtin_amdgcn_s_waitcnt(0x0F70);   // vmcnt(0): LDS tile ready

        const int itg0 = ss * 8;
        // prefetch iter 0's hF/e2
        bf16x8 pb0, pb1, pb2, pb3; float4 pea, peb;
        {
            const size_t ito = (size_t)itg0 * 2048;
            pb0 = *(const bf16x8*)(hfp + ito);
            pb1 = *(const bf16x8*)(hfp + ito + 512);
            pb2 = *(const bf16x8*)(hfp + ito + 1024);
            pb3 = *(const bf16x8*)(hfp + ito + 1536);
            const int jb = cb0 + quad * 8;
            pea = *(const float4*)(e2 + jb);
            peb = *(const float4*)(e2 + jb + 4);
        }
        #pragma unroll
        for (int p = 0; p < 8; ++p) {
            const bf16x8 b0 = pb0, b1 = pb1, b2 = pb2, b3 = pb3;
            const float4 ea = pea, eb = peb;
            if (p < 7) {   // issue iter p+1's loads BEFORE consuming iter p
                const size_t ito = (size_t)(itg0 + p + 1) * 2048;
                pb0 = *(const bf16x8*)(hfp + ito);
                pb1 = *(const bf16x8*)(hfp + ito + 512);
                pb2 = *(const bf16x8*)(hfp + ito + 1024);
                pb3 = *(const bf16x8*)(hfp + ito + 1536);
                const int jb = cb0 + (p + 1) * 32 + quad * 8;
                pea = *(const float4*)(e2 + jb);
                peb = *(const float4*)(e2 + jb + 4);
            }
            const int4 m0 = *(const int4*)(swm + p * 128 + quad * 32);
            const int4 m1 = *(const int4*)(swm + p * 128 + quad * 32 + 16);

            float s0 = er + ea.x; s0 = s0 > 0.f ? s0 : ALPHA * s0;
            float s1 = er + ea.y; s1 = s1 > 0.f ? s1 : ALPHA * s1;
            float s2 = er + ea.z; s2 = s2 > 0.f ? s2 : ALPHA * s2;
            float s3 = er + ea.w; s3 = s3 > 0.f ? s3 : ALPHA * s3;
            float s4 = er + eb.x; s4 = s4 > 0.f ? s4 : ALPHA * s4;
            float s5 = er + eb.y; s5 = s5 > 0.f ? s5 : ALPHA * s5;
            float s6 = er + eb.z; s6 = s6 > 0.f ? s6 : ALPHA * s6;
            float s7 = er + eb.w; s7 = s7 > 0.f ? s7 : ALPHA * s7;
            const float p0 = m0.x ? __expf(s0) : 0.f;
            const float p1 = m0.y ? __expf(s1) : 0.f;
            const float p2 = m0.z ? __expf(s2) : 0.f;
            const float p3 = m0.w ? __expf(s3) : 0.f;
            const float p4 = m1.x ? __expf(s4) : 0.f;
            const float p5 = m1.y ? __expf(s5) : 0.f;
            const float p6 = m1.z ? __expf(s6) : 0.f;
            const float p7 = m1.w ? __expf(s7) : 0.f;

            union { bf16x8 v; __hip_bfloat162 h2[4]; } af;
            af.h2[0] = __float22bfloat162_rn(make_float2(p0, p1));
            af.h2[1] = __float22bfloat162_rn(make_float2(p2, p3));
            af.h2[2] = __float22bfloat162_rn(make_float2(p4, p5));
            af.h2[3] = __float22bfloat162_rn(make_float2(p6, p7));

            lsum += ((p0 + p1) + (p2 + p3)) + ((p4 + p5) + (p6 + p7));

            acc0 = __builtin_amdgcn_mfma_f32_16x16x32_bf16(af.v, b0, acc0, 0, 0, 0);
            acc1 = __builtin_amdgcn_mfma_f32_16x16x32_bf16(af.v, b1, acc1, 0, 0, 0);
            acc2 = __builtin_amdgcn_mfma_f32_16x16x32_bf16(af.v, b2, acc2, 0, 0, 0);
            acc3 = __builtin_amdgcn_mfma_f32_16x16x32_bf16(af.v, b3, acc3, 0, 0, 0);
        }
    }

    // per-wave row sums: row m's columns live in lanes m, m+16, m+32, m+48
    lsum += __shfl_xor(lsum, 16);
    lsum += __shfl_xor(lsum, 32);
    if (quad == 0) lw[wave][m] = lsum;

    // ---- cross-wave combine in LDS (alias over dead mask buffers) ----
    __syncthreads();   // all DMAs drained (each wave did vmcnt(0)); buffers dead
    float* cw = (float*)smem;   // [wave][row][col] = [4][16][64] fp32, 16 KB
    #pragma unroll
    for (int reg = 0; reg < 4; ++reg) {
        float* rbase = cw + (wave * 16 + quad * 4 + reg) * 64;
        rbase[m     ] = acc0[reg];
        rbase[m + 16] = acc1[reg];
        rbase[m + 32] = acc2[reg];
        rbase[m + 48] = acc3[reg];
    }
    __syncthreads();
    #pragma unroll
    for (int rr = 0; rr < 4; ++rr) {
        const int idx = rr * 256 + t;          // 0..1023
        const int r = idx >> 6, c = idx & 63;
        // sum order w=0..3 == old k_reduce s-loop -> identical numerics
        float s = ((cw[(0 * 16 + r) * 64 + c] + cw[(1 * 16 + r) * 64 + c])
                +   cw[(2 * 16 + r) * 64 + c]) + cw[(3 * 16 + r) * 64 + c];
        float l = ((lw[0][r] + lw[1][r]) + lw[2][r]) + lw[3][r];
        out[(size_t)(i0 + r) * D + c] = s / l;
    }
}

extern "C" void kernel_launch(void* const* d_in, const int* in_sizes, int n_in,
                              void* d_out, int out_size, void* d_ws, size_t ws_size,
                              hipStream_t stream) {
    const float* x     = (const float*)d_in[0];
    const int*   mask  = (const int*)d_in[1];
    const float* trans = (const float*)d_in[2];
    const float* attn  = (const float*)d_in[3];
    float* out = (float*)d_out;

    char* ws = (char*)d_ws;
    __hip_bfloat16* hF = (__hip_bfloat16*)ws;                 // 1 MB
    char* p = ws + (size_t)D * N * sizeof(__hip_bfloat16);
    float* e1 = (float*)p;            p += (size_t)N * sizeof(float);
    float* e2 = (float*)p;            p += (size_t)N * sizeof(float);

    k_h_e<<<N / 8, 256, 0, stream>>>(x, trans, attn, hF, e1, e2);
    k_attn<<<N / 16, 256, 0, stream>>>(mask, hF, e1, e2, out);
}